// Round 1
// baseline (182.211 us; speedup 1.0000x reference)
//
#include <hip/hip_runtime.h>
#include <math.h>

#define DM 512
#define LSEQ 8192
#define NV 8
#define TOK 1608
#define RR 32          // rows (patches) per block

// token offset of each variable's segment, and its patch count
__device__ const int d_tokoff[8]   = {0, 513, 1026, 1155, 1284, 1413, 1542, 1575};
__device__ const int d_nps[8]      = {512, 512, 128, 128, 128, 128, 32, 32};
// cumulative patch-block counts per variable: chunks_v = n_p/32, times B=32 batches
__device__ const int d_cumblk[9]   = {0, 512, 1024, 1152, 1280, 1408, 1536, 1568, 1600};
__device__ const int d_lgchunks[8] = {4, 4, 2, 2, 2, 2, 0, 0};   // log2(n_p/32)

// ---------------------------------------------------------------------------
// Kernel 1: build sinusoidal positional-embedding table pe[512][512] (fp32).
// Matches numpy: div = exp((d&~1) * (-ln(10000)/512)); even d -> sin, odd -> cos
// ---------------------------------------------------------------------------
__global__ __launch_bounds__(512) void build_pe_kernel(float* __restrict__ pe) {
    int idx = blockIdx.x * 512 + threadIdx.x;     // 512*512 entries
    int i = idx >> 9;
    int d = idx & (DM - 1);
    const float c = -9.210340371976184f / 512.0f; // -ln(10000)/D
    float div = expf((float)(d & ~1) * c);
    float ang = (float)i * div;
    pe[idx] = (d & 1) ? cosf(ang) : sinf(ang);
}

// ---------------------------------------------------------------------------
// Per-variable patch embedding: one block = 32 consecutive patches of one
// (variable, batch). 512 threads, thread = output column d.
// ---------------------------------------------------------------------------
template<int PL, int SF>
__device__ __forceinline__ void patch_block(
    const float* __restrict__ x, const float* __restrict__ w,
    const float* __restrict__ bias, const float* __restrict__ chan,
    const float* __restrict__ pe, float* __restrict__ out,
    int v, int b, int chunk, int tokoff)
{
    extern __shared__ float lds[];                // RR*PL floats (<=16 KB)
    const int i0 = chunk * RR;

    // stage the 32 patches (packed, sampling folded in) into LDS.
    // packed index t = r*PL + j  <->  x offset t*SF  (since patch stride = PL*SF)
    const float* xb = x + ((size_t)b * NV + v) * LSEQ + (size_t)i0 * (PL * SF);
    for (int t = threadIdx.x; t < RR * PL; t += 512)
        lds[t] = xb[t * SF];
    __syncthreads();

    const int d = threadIdx.x;

    // weight row for this output column -> registers (amortized over 32 rows)
    float wreg[PL];
    {
        const float4* wd = reinterpret_cast<const float4*>(w + (size_t)d * PL);
#pragma unroll
        for (int q = 0; q < PL / 4; ++q) {
            float4 t4 = wd[q];
            wreg[4*q+0] = t4.x; wreg[4*q+1] = t4.y;
            wreg[4*q+2] = t4.z; wreg[4*q+3] = t4.w;
        }
    }

    const float bs = bias[d] + chan[v * DM + d];
    float* orow = out + ((size_t)b * TOK + tokoff + i0) * DM + d;
    const float* perow = pe + (size_t)i0 * DM + d;

#pragma unroll 4
    for (int r = 0; r < RR; ++r) {
        // broadcast float4 reads from LDS (same addr across wave -> no conflict)
        const float4* lp = reinterpret_cast<const float4*>(&lds[r * PL]);
        float a0 = 0.f, a1 = 0.f, a2 = 0.f, a3 = 0.f;
#pragma unroll
        for (int q = 0; q < PL / 4; ++q) {
            float4 pv = lp[q];
            float t = fmaf(pv.w, wreg[4*q+3],
                      fmaf(pv.z, wreg[4*q+2],
                      fmaf(pv.y, wreg[4*q+1],
                           pv.x * wreg[4*q+0])));
            if ((q & 3) == 0) a0 += t;
            else if ((q & 3) == 1) a1 += t;
            else if ((q & 3) == 2) a2 += t;
            else a3 += t;
        }
        float acc = (a0 + a1) + (a2 + a3);
        orow[(size_t)r * DM] = acc + bs + perow[(size_t)r * DM];
    }
}

// ---------------------------------------------------------------------------
// Main fused kernel. Blocks [0,1600): patch GEMM work. Blocks [1600,1856):
// global-token rows (one row per block).
// ---------------------------------------------------------------------------
__global__ __launch_bounds__(512) void patch_embed_kernel(
    const float* __restrict__ x,
    const float* __restrict__ w16,  const float* __restrict__ b16,
    const float* __restrict__ w32,  const float* __restrict__ b32,
    const float* __restrict__ w64,  const float* __restrict__ b64,
    const float* __restrict__ w128, const float* __restrict__ b128,
    const float* __restrict__ glb,  const float* __restrict__ chan,
    const float* __restrict__ pe,   float* __restrict__ out)
{
    int bid = blockIdx.x;
    int d = threadIdx.x;

    if (bid >= 1600) {                 // global-token rows: glb + channel_emb
        int row = bid - 1600;          // [0,256): v*32 + b
        int v = row >> 5;
        int b = row & 31;
        size_t o = ((size_t)b * TOK + d_tokoff[v] + d_nps[v]) * DM + d;
        out[o] = glb[d] + chan[v * DM + d];
        return;
    }

    // locate variable segment (block-uniform scalar search)
    int v = 0;
    while (bid >= d_cumblk[v + 1]) ++v;
    int local = bid - d_cumblk[v];
    int lg = d_lgchunks[v];
    int b = local >> lg;
    int chunk = local & ((1 << lg) - 1);
    int tokoff = d_tokoff[v];

    switch (v) {
        case 0: patch_block<16, 1>(x, w16,  b16,  chan, pe, out, 0, b, chunk, tokoff); break;
        case 1: patch_block<16, 1>(x, w16,  b16,  chan, pe, out, 1, b, chunk, tokoff); break;
        case 2: patch_block<32, 2>(x, w32,  b32,  chan, pe, out, 2, b, chunk, tokoff); break;
        case 3: patch_block<32, 2>(x, w32,  b32,  chan, pe, out, 3, b, chunk, tokoff); break;
        case 4: patch_block<64, 1>(x, w64,  b64,  chan, pe, out, 4, b, chunk, tokoff); break;
        case 5: patch_block<64, 1>(x, w64,  b64,  chan, pe, out, 5, b, chunk, tokoff); break;
        case 6: patch_block<128,2>(x, w128, b128, chan, pe, out, 6, b, chunk, tokoff); break;
        case 7: patch_block<128,2>(x, w128, b128, chan, pe, out, 7, b, chunk, tokoff); break;
    }
}

extern "C" void kernel_launch(void* const* d_in, const int* in_sizes, int n_in,
                              void* d_out, int out_size, void* d_ws, size_t ws_size,
                              hipStream_t stream) {
    const float* x    = (const float*)d_in[0];
    const float* w16  = (const float*)d_in[1];
    const float* b16  = (const float*)d_in[2];
    const float* w32  = (const float*)d_in[3];
    const float* b32  = (const float*)d_in[4];
    const float* w64  = (const float*)d_in[5];
    const float* b64  = (const float*)d_in[6];
    const float* w128 = (const float*)d_in[7];
    const float* b128 = (const float*)d_in[8];
    const float* glb  = (const float*)d_in[9];
    const float* chan = (const float*)d_in[10];
    float* out = (float*)d_out;
    float* pe = (float*)d_ws;                  // 512*512*4 = 1 MB scratch

    hipLaunchKernelGGL(build_pe_kernel, dim3(512), dim3(512), 0, stream, pe);

    hipLaunchKernelGGL(patch_embed_kernel, dim3(1856), dim3(512),
                       RR * 128 * sizeof(float),   // 16 KB dynamic LDS (max PL)
                       stream,
                       x, w16, b16, w32, b32, w64, b64, w128, b128,
                       glb, chan, pe, out);
}

// Round 2
// 75.978 us; speedup vs baseline: 2.3982x; 2.3982x over previous
//
#include <hip/hip_runtime.h>
#include <math.h>

#define DM 512
#define LSEQ 8192
#define NV 8
#define TOK 1608
#define ROWS 16      // patch rows per block
#define NTHR 128     // threads per block; each thread owns 4 consecutive cols

// Segment order is heavy-first (PL=128 blocks scheduled earliest to kill the tail).
// seg -> v mapping: {6,7,4,5,2,3,0,1}
__device__ __constant__ int c_segv[8]   = {6, 7, 4, 5, 2, 3, 0, 1};
// blocks per seg = 32 batches * (n_p/16): 64,64,256,256,256,256,1024,1024
__device__ __constant__ int c_cum[9]    = {0, 64, 128, 384, 640, 896, 1152, 2176, 3200};
__device__ __constant__ int c_lgch[8]   = {1, 1, 3, 3, 3, 3, 5, 5};   // log2(chunks per batch)
// indexed by v (not seg):
__device__ __constant__ int c_tokoff[8] = {0, 513, 1026, 1155, 1284, 1413, 1542, 1575};
__device__ __constant__ int c_np[8]     = {512, 512, 128, 128, 128, 128, 32, 32};

// ---------------------------------------------------------------------------
// sinusoidal positional-embedding table pe[512][512] (fp32), numpy-matched
// ---------------------------------------------------------------------------
__global__ __launch_bounds__(512) void build_pe_kernel(float* __restrict__ pe) {
    int idx = blockIdx.x * 512 + threadIdx.x;
    int i = idx >> 9;
    int d = idx & (DM - 1);
    const float c = -9.210340371976184f / 512.0f;  // -ln(10000)/D
    float div = expf((float)(d & ~1) * c);
    float ang = (float)i * div;
    pe[idx] = (d & 1) ? cosf(ang) : sinf(ang);
}

// ---------------------------------------------------------------------------
// One block: ROWS=16 patches x 512 cols. Thread t -> cols 4t..4t+3.
// acc[16][4] persistent (64 VGPR, static indices). K chunked by 4 floats.
// Each broadcast ds_read_b128 feeds 16 FMAs.
// ---------------------------------------------------------------------------
template<int PL, int SF>
__device__ __forceinline__ void patch_block(
    const float* __restrict__ x, const float* __restrict__ w,
    const float* __restrict__ bias, const float* __restrict__ chan,
    const float* __restrict__ pe, float* __restrict__ out,
    int v, int b, int chunk, int tokoff)
{
    extern __shared__ float lds[];               // ROWS*PL floats, <= 8 KB
    const int i0 = chunk * ROWS;
    constexpr int NE = ROWS * PL;

    // stage 16 packed patches (sampling folded) into LDS
    const float* xb = x + ((size_t)b * NV + v) * LSEQ + (size_t)i0 * (PL * SF);
    if (SF == 1) {
        const float4* xs = reinterpret_cast<const float4*>(xb);
        float4* ls = reinterpret_cast<float4*>(lds);
        for (int t = threadIdx.x; t < NE / 4; t += NTHR) ls[t] = xs[t];
    } else {
        for (int t = threadIdx.x; t < NE; t += NTHR) lds[t] = xb[t * SF];
    }
    __syncthreads();

    const int d4 = threadIdx.x << 2;

    float4 bc;
    {
        float4 bb = *reinterpret_cast<const float4*>(bias + d4);
        float4 cc = *reinterpret_cast<const float4*>(chan + v * DM + d4);
        bc.x = bb.x + cc.x; bc.y = bb.y + cc.y;
        bc.z = bb.z + cc.z; bc.w = bb.w + cc.w;
    }

    float acc[ROWS][4];
#pragma unroll
    for (int r = 0; r < ROWS; ++r) {
        acc[r][0] = 0.f; acc[r][1] = 0.f; acc[r][2] = 0.f; acc[r][3] = 0.f;
    }

    const float* wr0 = w + (size_t)(d4 + 0) * PL;
    const float* wr1 = w + (size_t)(d4 + 1) * PL;
    const float* wr2 = w + (size_t)(d4 + 2) * PL;
    const float* wr3 = w + (size_t)(d4 + 3) * PL;

    for (int kc = 0; kc < PL / 4; ++kc) {
        float4 w0 = *reinterpret_cast<const float4*>(wr0 + kc * 4);
        float4 w1 = *reinterpret_cast<const float4*>(wr1 + kc * 4);
        float4 w2 = *reinterpret_cast<const float4*>(wr2 + kc * 4);
        float4 w3 = *reinterpret_cast<const float4*>(wr3 + kc * 4);
#pragma unroll
        for (int r = 0; r < ROWS; ++r) {
            float4 p = *reinterpret_cast<const float4*>(&lds[r * PL + kc * 4]);
            acc[r][0] = fmaf(p.w, w0.w, fmaf(p.z, w0.z, fmaf(p.y, w0.y, fmaf(p.x, w0.x, acc[r][0]))));
            acc[r][1] = fmaf(p.w, w1.w, fmaf(p.z, w1.z, fmaf(p.y, w1.y, fmaf(p.x, w1.x, acc[r][1]))));
            acc[r][2] = fmaf(p.w, w2.w, fmaf(p.z, w2.z, fmaf(p.y, w2.y, fmaf(p.x, w2.x, acc[r][2]))));
            acc[r][3] = fmaf(p.w, w3.w, fmaf(p.z, w3.z, fmaf(p.y, w3.y, fmaf(p.x, w3.x, acc[r][3]))));
        }
    }

    float* ob = out + ((size_t)(b * TOK + tokoff + i0)) * DM + d4;
    const float* pb = pe + (size_t)i0 * DM + d4;
#pragma unroll
    for (int r = 0; r < ROWS; ++r) {
        float4 pv = *reinterpret_cast<const float4*>(pb + (size_t)r * DM);
        float4 o;
        o.x = acc[r][0] + bc.x + pv.x;
        o.y = acc[r][1] + bc.y + pv.y;
        o.z = acc[r][2] + bc.z + pv.z;
        o.w = acc[r][3] + bc.w + pv.w;
        *reinterpret_cast<float4*>(ob + (size_t)r * DM) = o;
    }
}

// ---------------------------------------------------------------------------
// Blocks [0,3200): patch GEMM. Blocks [3200,3208): global-token rows (one v
// each, all 32 batches).
// ---------------------------------------------------------------------------
__global__ __launch_bounds__(NTHR, 4) void patch_embed_kernel(
    const float* __restrict__ x,
    const float* __restrict__ w16,  const float* __restrict__ b16,
    const float* __restrict__ w32,  const float* __restrict__ b32,
    const float* __restrict__ w64,  const float* __restrict__ b64,
    const float* __restrict__ w128, const float* __restrict__ b128,
    const float* __restrict__ glb,  const float* __restrict__ chan,
    const float* __restrict__ pe,   float* __restrict__ out)
{
    int bid = blockIdx.x;
    const int d4 = threadIdx.x << 2;

    if (bid >= 3200) {                       // global-token rows
        int v = bid - 3200;
        float4 g = *reinterpret_cast<const float4*>(glb + d4);
        float4 c = *reinterpret_cast<const float4*>(chan + v * DM + d4);
        float4 o;
        o.x = g.x + c.x; o.y = g.y + c.y; o.z = g.z + c.z; o.w = g.w + c.w;
        int row0 = c_tokoff[v] + c_np[v];
        for (int b = 0; b < 32; ++b)
            *reinterpret_cast<float4*>(out + ((size_t)(b * TOK + row0)) * DM + d4) = o;
        return;
    }

    int seg = 0;
    while (bid >= c_cum[seg + 1]) ++seg;     // 8-entry block-uniform search
    int local = bid - c_cum[seg];
    int v = c_segv[seg];
    int lg = c_lgch[seg];
    int b = local >> lg;
    int chunk = local & ((1 << lg) - 1);
    int tokoff = c_tokoff[v];

    switch (v) {
        case 0: patch_block<16, 1>(x, w16,  b16,  chan, pe, out, 0, b, chunk, tokoff); break;
        case 1: patch_block<16, 1>(x, w16,  b16,  chan, pe, out, 1, b, chunk, tokoff); break;
        case 2: patch_block<32, 2>(x, w32,  b32,  chan, pe, out, 2, b, chunk, tokoff); break;
        case 3: patch_block<32, 2>(x, w32,  b32,  chan, pe, out, 3, b, chunk, tokoff); break;
        case 4: patch_block<64, 1>(x, w64,  b64,  chan, pe, out, 4, b, chunk, tokoff); break;
        case 5: patch_block<64, 1>(x, w64,  b64,  chan, pe, out, 5, b, chunk, tokoff); break;
        case 6: patch_block<128,2>(x, w128, b128, chan, pe, out, 6, b, chunk, tokoff); break;
        case 7: patch_block<128,2>(x, w128, b128, chan, pe, out, 7, b, chunk, tokoff); break;
    }
}

extern "C" void kernel_launch(void* const* d_in, const int* in_sizes, int n_in,
                              void* d_out, int out_size, void* d_ws, size_t ws_size,
                              hipStream_t stream) {
    const float* x    = (const float*)d_in[0];
    const float* w16  = (const float*)d_in[1];
    const float* b16  = (const float*)d_in[2];
    const float* w32  = (const float*)d_in[3];
    const float* b32  = (const float*)d_in[4];
    const float* w64  = (const float*)d_in[5];
    const float* b64  = (const float*)d_in[6];
    const float* w128 = (const float*)d_in[7];
    const float* b128 = (const float*)d_in[8];
    const float* glb  = (const float*)d_in[9];
    const float* chan = (const float*)d_in[10];
    float* out = (float*)d_out;
    float* pe = (float*)d_ws;                  // 512*512*4 = 1 MB scratch

    hipLaunchKernelGGL(build_pe_kernel, dim3(512), dim3(512), 0, stream, pe);

    hipLaunchKernelGGL(patch_embed_kernel, dim3(3208), dim3(NTHR),
                       ROWS * 128 * sizeof(float),   // 8 KB dynamic LDS (max PL)
                       stream,
                       x, w16, b16, w32, b32, w64, b64, w128, b128,
                       glb, chan, pe, out);
}

// Round 3
// 62.059 us; speedup vs baseline: 2.9361x; 1.2243x over previous
//
#include <hip/hip_runtime.h>
#include <math.h>

#define DM 512
#define LSEQ 8192
#define NV 8
#define TOK 1608
#define ROWS 16      // patch rows per block
#define NTHR 256     // threads per block; each thread owns 2 consecutive cols

// Heavy-first segment order (PL=128 first to kill the scheduling tail).
// seg -> v: {6,7,4,5,2,3,0,1}
__device__ __constant__ int c_segv[8]   = {6, 7, 4, 5, 2, 3, 0, 1};
// blocks per seg = 32 batches * (n_p/16): 64,64,256,256,256,256,1024,1024
__device__ __constant__ int c_cum[9]    = {0, 64, 128, 384, 640, 896, 1152, 2176, 3200};
__device__ __constant__ int c_lgch[8]   = {1, 1, 3, 3, 3, 3, 5, 5};   // log2(chunks/batch)
// indexed by v:
__device__ __constant__ int c_tokoff[8] = {0, 513, 1026, 1155, 1284, 1413, 1542, 1575};
__device__ __constant__ int c_np[8]     = {512, 512, 128, 128, 128, 128, 32, 32};
__device__ __constant__ int c_pl[8]     = {16, 16, 32, 32, 64, 64, 128, 128};
__device__ __constant__ int c_sf[8]     = {1, 1, 2, 2, 1, 1, 2, 2};

// ---------------------------------------------------------------------------
// sinusoidal positional-embedding table pe[512][512] (fp32), numpy-matched
// ---------------------------------------------------------------------------
__global__ __launch_bounds__(512) void build_pe_kernel(float* __restrict__ pe) {
    int idx = blockIdx.x * 512 + threadIdx.x;
    int i = idx >> 9;
    int d = idx & (DM - 1);
    const float c = -9.210340371976184f / 512.0f;  // -ln(10000)/D
    float div = expf((float)(d & ~1) * c);
    float ang = (float)i * div;
    pe[idx] = (d & 1) ? cosf(ang) : sinf(ang);
}

// inner FMA burst for one K-chunk: 16 rows x 2 cols x 4 MACs, LDS broadcast
#define KC_BODY(A0, A1, KC)                                                        \
    _Pragma("unroll")                                                              \
    for (int r = 0; r < ROWS; ++r) {                                               \
        float4 p = *reinterpret_cast<const float4*>(&lds[r * pl + (KC) * 4]);      \
        acc[r][0] = fmaf(p.w, (A0).w, fmaf(p.z, (A0).z,                            \
                    fmaf(p.y, (A0).y, fmaf(p.x, (A0).x, acc[r][0]))));             \
        acc[r][1] = fmaf(p.w, (A1).w, fmaf(p.z, (A1).z,                            \
                    fmaf(p.y, (A1).y, fmaf(p.x, (A1).x, acc[r][1]))));             \
    }

__global__ __launch_bounds__(NTHR, 6) void patch_embed_kernel(
    const float* __restrict__ x,
    const float* __restrict__ w16,  const float* __restrict__ b16,
    const float* __restrict__ w32,  const float* __restrict__ b32,
    const float* __restrict__ w64,  const float* __restrict__ b64,
    const float* __restrict__ w128, const float* __restrict__ b128,
    const float* __restrict__ glb,  const float* __restrict__ chan,
    const float* __restrict__ pe,   float* __restrict__ out)
{
    extern __shared__ float lds[];               // ROWS*pl floats, <= 8 KB
    int bid = blockIdx.x;
    const int d2 = threadIdx.x << 1;

    if (bid >= 3200) {                           // global-token rows (8 blocks)
        int v = bid - 3200;
        float2 g = *reinterpret_cast<const float2*>(glb + d2);
        float2 c = *reinterpret_cast<const float2*>(chan + v * DM + d2);
        float2 o; o.x = g.x + c.x; o.y = g.y + c.y;
        int row0 = c_tokoff[v] + c_np[v];
        for (int b = 0; b < 32; ++b)
            *reinterpret_cast<float2*>(out + ((size_t)(b * TOK + row0)) * DM + d2) = o;
        return;
    }

    // ---- block -> (v, b, chunk), block-uniform scalar work ----
    int seg = 0;
    while (bid >= c_cum[seg + 1]) ++seg;
    int local = bid - c_cum[seg];
    int v = c_segv[seg];
    int lg = c_lgch[seg];
    int b = local >> lg;
    int chunk = local & ((1 << lg) - 1);
    const int pl = c_pl[v];
    const int sf = c_sf[v];
    const int i0 = chunk * ROWS;

    const float* w    = (pl == 16) ? w16 : (pl == 32) ? w32 : (pl == 64) ? w64 : w128;
    const float* bias = (pl == 16) ? b16 : (pl == 32) ? b32 : (pl == 64) ? b64 : b128;

    // ---- stage ROWS packed patches (sampling folded) into LDS ----
    const int ne = ROWS * pl;
    const float* xb = x + ((size_t)b * NV + v) * LSEQ + (size_t)i0 * (pl * sf);
    if (sf == 1) {
        const float4* xs = reinterpret_cast<const float4*>(xb);
        float4* ls = reinterpret_cast<float4*>(lds);
        for (int t = threadIdx.x; t < (ne >> 2); t += NTHR) ls[t] = xs[t];
    } else {
        // lds[t] = xb[2t]; handle 2 elems per float4 load (.x and .z)
        for (int t2 = threadIdx.x; t2 < (ne >> 1); t2 += NTHR) {
            float4 q = *reinterpret_cast<const float4*>(xb + 4 * t2);
            lds[2 * t2]     = q.x;
            lds[2 * t2 + 1] = q.z;
        }
    }
    __syncthreads();

    // ---- per-thread state ----
    float bc0, bc1;
    {
        float2 bb = *reinterpret_cast<const float2*>(bias + d2);
        float2 cc = *reinterpret_cast<const float2*>(chan + v * DM + d2);
        bc0 = bb.x + cc.x; bc1 = bb.y + cc.y;
    }

    float acc[ROWS][2];
#pragma unroll
    for (int r = 0; r < ROWS; ++r) { acc[r][0] = 0.f; acc[r][1] = 0.f; }

    const float* wr0 = w + (size_t)d2 * pl;      // weight rows d2, d2+1
    const float* wr1 = wr0 + pl;

    // ---- K loop, weight loads software-pipelined one chunk ahead ----
    const int nkc = pl >> 2;
    float4 a0 = *reinterpret_cast<const float4*>(wr0);
    float4 a1 = *reinterpret_cast<const float4*>(wr1);
    for (int kc = 0; kc < nkc - 1; ++kc) {
        float4 n0 = *reinterpret_cast<const float4*>(wr0 + (kc + 1) * 4);
        float4 n1 = *reinterpret_cast<const float4*>(wr1 + (kc + 1) * 4);
        KC_BODY(a0, a1, kc)
        a0 = n0; a1 = n1;
    }
    KC_BODY(a0, a1, nkc - 1)                     // peeled last chunk (no OOB prefetch)

    // ---- epilogue: + bias + channel + pe, coalesced float2 stores ----
    float* ob = out + ((size_t)(b * TOK + c_tokoff[v] + i0)) * DM + d2;
    const float* pb = pe + (size_t)i0 * DM + d2;
#pragma unroll
    for (int r = 0; r < ROWS; ++r) {
        float2 pv = *reinterpret_cast<const float2*>(pb + (size_t)r * DM);
        float2 o;
        o.x = acc[r][0] + bc0 + pv.x;
        o.y = acc[r][1] + bc1 + pv.y;
        *reinterpret_cast<float2*>(ob + (size_t)r * DM) = o;
    }
}

extern "C" void kernel_launch(void* const* d_in, const int* in_sizes, int n_in,
                              void* d_out, int out_size, void* d_ws, size_t ws_size,
                              hipStream_t stream) {
    const float* x    = (const float*)d_in[0];
    const float* w16  = (const float*)d_in[1];
    const float* b16  = (const float*)d_in[2];
    const float* w32  = (const float*)d_in[3];
    const float* b32  = (const float*)d_in[4];
    const float* w64  = (const float*)d_in[5];
    const float* b64  = (const float*)d_in[6];
    const float* w128 = (const float*)d_in[7];
    const float* b128 = (const float*)d_in[8];
    const float* glb  = (const float*)d_in[9];
    const float* chan = (const float*)d_in[10];
    float* out = (float*)d_out;
    float* pe = (float*)d_ws;                  // 512*512*4 = 1 MB scratch

    hipLaunchKernelGGL(build_pe_kernel, dim3(512), dim3(512), 0, stream, pe);

    hipLaunchKernelGGL(patch_embed_kernel, dim3(3208), dim3(NTHR),
                       ROWS * 128 * sizeof(float),   // 8 KB dynamic LDS (max pl)
                       stream,
                       x, w16, b16, w32, b32, w64, b64, w128, b128,
                       glb, chan, pe, out);
}

// Round 4
// 57.939 us; speedup vs baseline: 3.1449x; 1.0711x over previous
//
#include <hip/hip_runtime.h>
#include <math.h>

#define DM 512
#define LSEQ 8192
#define NV 8
#define TOK 1608
#define BROWS 32     // patch rows per block
#define NTHR 512     // 8 waves; thread tile = 4 rows x 8 cols

// Heavy-first segment order (pl=128 first). seg -> v: {6,7,4,5,2,3,0,1}
__device__ __constant__ int c_segv[8]   = {6, 7, 4, 5, 2, 3, 0, 1};
// blocks/seg = 32 batches * (n_p/32): 32,32,128,128,128,128,512,512
__device__ __constant__ int c_cum[9]    = {0, 32, 64, 192, 320, 448, 576, 1088, 1600};
__device__ __constant__ int c_lgch[8]   = {0, 0, 2, 2, 2, 2, 4, 4};   // log2(chunks/batch)
// indexed by v:
__device__ __constant__ int c_tokoff[8] = {0, 513, 1026, 1155, 1284, 1413, 1542, 1575};
__device__ __constant__ int c_np[8]     = {512, 512, 128, 128, 128, 128, 32, 32};
__device__ __constant__ int c_pl[8]     = {16, 16, 32, 32, 64, 64, 128, 128};
__device__ __constant__ int c_sf[8]     = {1, 1, 2, 2, 1, 1, 2, 2};
// transposed-weight offsets (floats, within d_ws) per v; pe occupies [0, 262144)
__device__ __constant__ int c_wtoff[8]  = {262144, 262144, 270336, 270336,
                                           286720, 286720, 319488, 319488};

// ---------------------------------------------------------------------------
// sinusoidal positional-embedding table pe[512][512] (fp32), numpy-matched
// ---------------------------------------------------------------------------
__global__ __launch_bounds__(512) void build_pe_kernel(float* __restrict__ pe) {
    int idx = blockIdx.x * 512 + threadIdx.x;
    int i = idx >> 9;
    int d = idx & (DM - 1);
    const float c = -9.210340371976184f / 512.0f;  // -ln(10000)/D
    float div = expf((float)(d & ~1) * c);
    float ang = (float)i * div;
    pe[idx] = (d & 1) ? cosf(ang) : sinf(ang);
}

// ---------------------------------------------------------------------------
// weight transpose: wt[pl][512] with wt[j][d] = w[d][j]; makes the main
// kernel's per-k weight loads lane-contiguous (coalesced float4 pairs).
// ---------------------------------------------------------------------------
__global__ __launch_bounds__(512) void transpose_w_kernel(
    const float* __restrict__ w16, const float* __restrict__ w32,
    const float* __restrict__ w64, const float* __restrict__ w128,
    float* __restrict__ ws)
{
    int j = blockIdx.x;          // 240 rows total across the 4 matrices
    int d = threadIdx.x;
    const float* w; int pl, row, off;
    if (j < 16)       { w = w16;  pl = 16;  row = j;       off = 262144; }
    else if (j < 48)  { w = w32;  pl = 32;  row = j - 16;  off = 270336; }
    else if (j < 112) { w = w64;  pl = 64;  row = j - 48;  off = 286720; }
    else              { w = w128; pl = 128; row = j - 112; off = 319488; }
    ws[off + row * DM + d] = w[d * pl + row];
}

// ---------------------------------------------------------------------------
// Main kernel. Blocks [0,1600): 32 rows x 512 cols each; thread = 4r x 8c.
// Blocks [1600,1608): global-token rows.
// ---------------------------------------------------------------------------
__global__ __launch_bounds__(NTHR, 4) void patch_embed_kernel(
    const float* __restrict__ x,
    const float* __restrict__ b16,  const float* __restrict__ b32,
    const float* __restrict__ b64,  const float* __restrict__ b128,
    const float* __restrict__ glb,  const float* __restrict__ chan,
    const float* __restrict__ ws,   float* __restrict__ out)
{
    extern __shared__ float lds[];               // BROWS*pl floats, <= 16 KB
    int bid = blockIdx.x;

    if (bid >= 1600) {                           // global-token rows (8 blocks)
        int v = bid - 1600;
        int d = threadIdx.x;
        float o = glb[d] + chan[v * DM + d];
        int row0 = c_tokoff[v] + c_np[v];
        for (int b = 0; b < 32; ++b)
            out[((size_t)(b * TOK + row0)) * DM + d] = o;
        return;
    }

    // ---- block -> (v, b, chunk), block-uniform scalar work ----
    int seg = 0;
    while (bid >= c_cum[seg + 1]) ++seg;
    int local = bid - c_cum[seg];
    int v = c_segv[seg];
    int lg = c_lgch[seg];
    int b = local >> lg;
    int chunk = local & ((1 << lg) - 1);
    const int pl = c_pl[v];
    const int sf = c_sf[v];
    const int i0 = chunk * BROWS;

    // ---- stage BROWS packed patches (sampling folded) into LDS ----
    const int ne = BROWS * pl;
    const float* xb = x + ((size_t)b * NV + v) * LSEQ + (size_t)i0 * (pl * sf);
    if (sf == 1) {
        const float4* xs = reinterpret_cast<const float4*>(xb);
        float4* ls = reinterpret_cast<float4*>(lds);
        for (int t = threadIdx.x; t < (ne >> 2); t += NTHR) ls[t] = xs[t];
    } else {
        float2* ls = reinterpret_cast<float2*>(lds);
        for (int t2 = threadIdx.x; t2 < (ne >> 1); t2 += NTHR) {
            float4 q = *reinterpret_cast<const float4*>(xb + 4 * t2);
            float2 o; o.x = q.x; o.y = q.z;      // keep stride-2 samples
            ls[t2] = o;
        }
    }
    __syncthreads();

    // ---- per-thread geometry ----
    const int lane = threadIdx.x & 63;
    const int wv   = threadIdx.x >> 6;           // wave id -> row group
    const int c0   = lane << 3;                  // 8 consecutive cols
    const float* ldsrow = lds + (wv * 4) * pl;
    const float* wtv = ws + c_wtoff[v];          // wt[k][512]

    float acc[4][8];
#pragma unroll
    for (int r = 0; r < 4; ++r)
#pragma unroll
        for (int c = 0; c < 8; ++c) acc[r][c] = 0.f;

    const int nkc = pl >> 2;
    for (int kc = 0; kc < nkc; ++kc) {
        const int k0 = kc << 2;
        float4 wA[4], wB[4];                     // cols c0..3 / c0+4..7, k = k0..k0+3
#pragma unroll
        for (int k = 0; k < 4; ++k) {
            const float4* wp = reinterpret_cast<const float4*>(wtv + (size_t)(k0 + k) * DM + c0);
            wA[k] = wp[0]; wB[k] = wp[1];
        }
        float4 p[4];                             // 4 rows x 4 k (broadcast reads)
#pragma unroll
        for (int r = 0; r < 4; ++r)
            p[r] = *reinterpret_cast<const float4*>(ldsrow + r * pl + k0);
#pragma unroll
        for (int r = 0; r < 4; ++r) {
#pragma unroll
            for (int k = 0; k < 4; ++k) {
                float pk = (k == 0) ? p[r].x : (k == 1) ? p[r].y : (k == 2) ? p[r].z : p[r].w;
                acc[r][0] = fmaf(pk, wA[k].x, acc[r][0]);
                acc[r][1] = fmaf(pk, wA[k].y, acc[r][1]);
                acc[r][2] = fmaf(pk, wA[k].z, acc[r][2]);
                acc[r][3] = fmaf(pk, wA[k].w, acc[r][3]);
                acc[r][4] = fmaf(pk, wB[k].x, acc[r][4]);
                acc[r][5] = fmaf(pk, wB[k].y, acc[r][5]);
                acc[r][6] = fmaf(pk, wB[k].z, acc[r][6]);
                acc[r][7] = fmaf(pk, wB[k].w, acc[r][7]);
            }
        }
    }

    // ---- epilogue: + bias + channel + pe, float4-pair stores ----
    const float* bias = (pl == 16) ? b16 : (pl == 32) ? b32 : (pl == 64) ? b64 : b128;
    float4 bcA, bcB;
    {
        float4 ba = *reinterpret_cast<const float4*>(bias + c0);
        float4 bb = *reinterpret_cast<const float4*>(bias + c0 + 4);
        float4 ca = *reinterpret_cast<const float4*>(chan + v * DM + c0);
        float4 cb = *reinterpret_cast<const float4*>(chan + v * DM + c0 + 4);
        bcA.x = ba.x + ca.x; bcA.y = ba.y + ca.y; bcA.z = ba.z + ca.z; bcA.w = ba.w + ca.w;
        bcB.x = bb.x + cb.x; bcB.y = bb.y + cb.y; bcB.z = bb.z + cb.z; bcB.w = bb.w + cb.w;
    }

    const int row0 = i0 + wv * 4;
    float* ob = out + ((size_t)(b * TOK + c_tokoff[v] + row0)) * DM + c0;
    const float* pb = ws /*pe*/ + (size_t)row0 * DM + c0;
#pragma unroll
    for (int r = 0; r < 4; ++r) {
        float4 pA = *reinterpret_cast<const float4*>(pb + (size_t)r * DM);
        float4 pB = *reinterpret_cast<const float4*>(pb + (size_t)r * DM + 4);
        float4 oA, oB;
        oA.x = acc[r][0] + bcA.x + pA.x;
        oA.y = acc[r][1] + bcA.y + pA.y;
        oA.z = acc[r][2] + bcA.z + pA.z;
        oA.w = acc[r][3] + bcA.w + pA.w;
        oB.x = acc[r][4] + bcB.x + pB.x;
        oB.y = acc[r][5] + bcB.y + pB.y;
        oB.z = acc[r][6] + bcB.z + pB.z;
        oB.w = acc[r][7] + bcB.w + pB.w;
        *reinterpret_cast<float4*>(ob + (size_t)r * DM)     = oA;
        *reinterpret_cast<float4*>(ob + (size_t)r * DM + 4) = oB;
    }
}

extern "C" void kernel_launch(void* const* d_in, const int* in_sizes, int n_in,
                              void* d_out, int out_size, void* d_ws, size_t ws_size,
                              hipStream_t stream) {
    const float* x    = (const float*)d_in[0];
    const float* w16  = (const float*)d_in[1];
    const float* b16  = (const float*)d_in[2];
    const float* w32  = (const float*)d_in[3];
    const float* b32  = (const float*)d_in[4];
    const float* w64  = (const float*)d_in[5];
    const float* b64  = (const float*)d_in[6];
    const float* w128 = (const float*)d_in[7];
    const float* b128 = (const float*)d_in[8];
    const float* glb  = (const float*)d_in[9];
    const float* chan = (const float*)d_in[10];
    float* out = (float*)d_out;
    float* ws  = (float*)d_ws;   // pe[512][512] + wt16/32/64/128 = 1.47 MB

    hipLaunchKernelGGL(build_pe_kernel, dim3(512), dim3(512), 0, stream, ws);
    hipLaunchKernelGGL(transpose_w_kernel, dim3(240), dim3(512), 0, stream,
                       w16, w32, w64, w128, ws);
    hipLaunchKernelGGL(patch_embed_kernel, dim3(1608), dim3(NTHR),
                       BROWS * 128 * sizeof(float),   // 16 KB dynamic LDS (max pl)
                       stream,
                       x, b16, b32, b64, b128, glb, chan, ws, out);
}

// Round 5
// 42.840 us; speedup vs baseline: 4.2533x; 1.3525x over previous
//
#include <hip/hip_runtime.h>
#include <math.h>

#define DM 512
#define LSEQ 8192
#define NV 8
#define TOK 1608
#define BROWS 32     // patch rows per block
#define NTHR 256     // 4 waves; wave = 8 rows x 512 cols; thread = 8r x 8c

typedef _Float16 h2 __attribute__((ext_vector_type(2)));

// Heavy-first segment order (pl=128 first). seg -> v: {6,7,4,5,2,3,0,1}
__device__ __constant__ int c_segv[8]   = {6, 7, 4, 5, 2, 3, 0, 1};
// blocks/seg = 32 batches * (n_p/32): 32,32,128,128,128,128,512,512
__device__ __constant__ int c_cum[9]    = {0, 32, 64, 192, 320, 448, 576, 1088, 1600};
__device__ __constant__ int c_lgch[8]   = {0, 0, 2, 2, 2, 2, 4, 4};   // log2(chunks/batch)
// indexed by v:
__device__ __constant__ int c_tokoff[8] = {0, 513, 1026, 1155, 1284, 1413, 1542, 1575};
__device__ __constant__ int c_np[8]     = {512, 512, 128, 128, 128, 128, 32, 32};
__device__ __constant__ int c_pl[8]     = {16, 16, 32, 32, 64, 64, 128, 128};
__device__ __constant__ int c_sf[8]     = {1, 1, 2, 2, 1, 1, 2, 2};
// packed-half2-weight word offsets within d_ws per v; pe occupies words [0,262144)
__device__ __constant__ int c_wtoff[8]  = {262144, 262144, 266240, 266240,
                                           274432, 274432, 290816, 290816};

__device__ __forceinline__ float fdot2f(h2 a, h2 b, float c) {
#if __has_builtin(__builtin_amdgcn_fdot2)
    return __builtin_amdgcn_fdot2(a, b, c, false);
#else
    return fmaf((float)a.y, (float)b.y, fmaf((float)a.x, (float)b.x, c));
#endif
}
__device__ __forceinline__ h2 bch2(unsigned u) { return __builtin_bit_cast(h2, u); }

// ---------------------------------------------------------------------------
// Setup: blocks [0,512) build pe[512][512] fp32 (numpy-matched sinusoidal);
// blocks [512,632) pack transposed fp16 weights wt_h[k2][512] (half2 words).
// ---------------------------------------------------------------------------
__global__ __launch_bounds__(512) void setup_kernel(
    const float* __restrict__ w16, const float* __restrict__ w32,
    const float* __restrict__ w64, const float* __restrict__ w128,
    float* __restrict__ ws)
{
    int bid = blockIdx.x;
    int d = threadIdx.x;
    if (bid < 512) {
        int idx = bid * 512 + d;
        int i = idx >> 9;
        int dd = idx & (DM - 1);
        const float c = -9.210340371976184f / 512.0f;  // -ln(10000)/D
        float div = expf((float)(dd & ~1) * c);
        float ang = (float)i * div;
        ws[idx] = (dd & 1) ? cosf(ang) : sinf(ang);
        return;
    }
    int j = bid - 512;                 // 120 half2-rows across the 4 matrices
    const float* w; int pl, k2, off;
    if (j < 8)       { w = w16;  pl = 16;  k2 = j;      off = 262144; }
    else if (j < 24) { w = w32;  pl = 32;  k2 = j - 8;  off = 266240; }
    else if (j < 56) { w = w64;  pl = 64;  k2 = j - 24; off = 274432; }
    else             { w = w128; pl = 128; k2 = j - 56; off = 290816; }
    float2 p = *reinterpret_cast<const float2*>(w + (size_t)d * pl + 2 * k2);
    h2 h; h.x = (_Float16)p.x; h.y = (_Float16)p.y;
    reinterpret_cast<unsigned*>(ws)[off + k2 * DM + d] = __builtin_bit_cast(unsigned, h);
}

// ---------------------------------------------------------------------------
// Main kernel. Blocks [0,1600): 32 rows x 512 cols; thread = 8 rows x 8 cols,
// fp16 dot2 inner product, fp32 epilogue. Blocks [1600,1608): global tokens.
// ---------------------------------------------------------------------------
__global__ __launch_bounds__(NTHR) void patch_embed_kernel(
    const float* __restrict__ x,
    const float* __restrict__ b16,  const float* __restrict__ b32,
    const float* __restrict__ b64,  const float* __restrict__ b128,
    const float* __restrict__ glb,  const float* __restrict__ chan,
    const float* __restrict__ ws,   float* __restrict__ out)
{
    extern __shared__ float ldsf[];              // 32 rows * pl/2 half2 words, <= 8 KB
    unsigned* ldsu = reinterpret_cast<unsigned*>(ldsf);
    int bid = blockIdx.x;
    const int tid = threadIdx.x;

    if (bid >= 1600) {                           // global-token rows (8 blocks)
        int v = bid - 1600;
        int d2 = tid << 1;
        float2 g = *reinterpret_cast<const float2*>(glb + d2);
        float2 c = *reinterpret_cast<const float2*>(chan + v * DM + d2);
        float2 o; o.x = g.x + c.x; o.y = g.y + c.y;
        int row0 = c_tokoff[v] + c_np[v];
        for (int b = 0; b < 32; ++b)
            *reinterpret_cast<float2*>(out + ((size_t)(b * TOK + row0)) * DM + d2) = o;
        return;
    }

    // ---- block -> (v, b, chunk), block-uniform scalar work ----
    int seg = 0;
    while (bid >= c_cum[seg + 1]) ++seg;
    int local = bid - c_cum[seg];
    int v = c_segv[seg];
    int lg = c_lgch[seg];
    int b = local >> lg;
    int chunk = local & ((1 << lg) - 1);
    const int pl = c_pl[v];
    const int sf = c_sf[v];
    const int pl2 = pl >> 1;
    const int i0 = chunk * BROWS;

    // ---- stage 32 packed patches into LDS as half2 (sampling folded) ----
    const int ne2 = (BROWS * pl) >> 1;           // half2 words
    const float* xb = x + ((size_t)b * NV + v) * LSEQ + (size_t)i0 * (pl * sf);
    if (sf == 1) {
        for (int t = tid; t < (ne2 >> 1); t += NTHR) {   // t = one float4 = 2 words
            float4 q = *reinterpret_cast<const float4*>(xb + 4 * t);
            h2 a; a.x = (_Float16)q.x; a.y = (_Float16)q.y;
            h2 c; c.x = (_Float16)q.z; c.y = (_Float16)q.w;
            uint2 o; o.x = __builtin_bit_cast(unsigned, a);
            o.y = __builtin_bit_cast(unsigned, c);
            *reinterpret_cast<uint2*>(ldsu + 2 * t) = o;
        }
    } else {
        for (int p = tid; p < ne2; p += NTHR) {          // one word per float4
            float4 q = *reinterpret_cast<const float4*>(xb + 4 * p);
            h2 a; a.x = (_Float16)q.x; a.y = (_Float16)q.z;
            ldsu[p] = __builtin_bit_cast(unsigned, a);
        }
    }
    __syncthreads();

    // ---- per-thread geometry ----
    const int lane = tid & 63;
    const int wv   = tid >> 6;                   // wave -> rows [8wv, 8wv+8)
    const int c0   = lane << 3;                  // 8 consecutive cols
    const unsigned* prow = ldsu + (wv * 8) * pl2;
    const unsigned* wtv  = reinterpret_cast<const unsigned*>(ws) + c_wtoff[v];

    float acc[8][8];
#pragma unroll
    for (int r = 0; r < 8; ++r)
#pragma unroll
        for (int c = 0; c < 8; ++c) acc[r][c] = 0.f;

    // ---- K loop: 2 half2-rows (4 k) per iter; W prefetched one iter ahead ----
    uint4 wa0 = *reinterpret_cast<const uint4*>(wtv + c0);
    uint4 wb0 = *reinterpret_cast<const uint4*>(wtv + c0 + 4);
    uint4 wa1 = *reinterpret_cast<const uint4*>(wtv + DM + c0);
    uint4 wb1 = *reinterpret_cast<const uint4*>(wtv + DM + c0 + 4);

    for (int k2 = 0; k2 < pl2; k2 += 2) {
        uint4 na0, nb0, na1, nb1;
        if (k2 + 2 < pl2) {
            const unsigned* wn = wtv + (k2 + 2) * DM;
            na0 = *reinterpret_cast<const uint4*>(wn + c0);
            nb0 = *reinterpret_cast<const uint4*>(wn + c0 + 4);
            na1 = *reinterpret_cast<const uint4*>(wn + DM + c0);
            nb1 = *reinterpret_cast<const uint4*>(wn + DM + c0 + 4);
        }
        uint2 pr[8];
#pragma unroll
        for (int r = 0; r < 8; ++r)
            pr[r] = *reinterpret_cast<const uint2*>(prow + r * pl2 + k2);
#pragma unroll
        for (int r = 0; r < 8; ++r) {
            h2 p0 = bch2(pr[r].x);
            h2 p1 = bch2(pr[r].y);
            acc[r][0] = fdot2f(p1, bch2(wa1.x), fdot2f(p0, bch2(wa0.x), acc[r][0]));
            acc[r][1] = fdot2f(p1, bch2(wa1.y), fdot2f(p0, bch2(wa0.y), acc[r][1]));
            acc[r][2] = fdot2f(p1, bch2(wa1.z), fdot2f(p0, bch2(wa0.z), acc[r][2]));
            acc[r][3] = fdot2f(p1, bch2(wa1.w), fdot2f(p0, bch2(wa0.w), acc[r][3]));
            acc[r][4] = fdot2f(p1, bch2(wb1.x), fdot2f(p0, bch2(wb0.x), acc[r][4]));
            acc[r][5] = fdot2f(p1, bch2(wb1.y), fdot2f(p0, bch2(wb0.y), acc[r][5]));
            acc[r][6] = fdot2f(p1, bch2(wb1.z), fdot2f(p0, bch2(wb0.z), acc[r][6]));
            acc[r][7] = fdot2f(p1, bch2(wb1.w), fdot2f(p0, bch2(wb0.w), acc[r][7]));
        }
        wa0 = na0; wb0 = nb0; wa1 = na1; wb1 = nb1;
    }

    // ---- fp32 epilogue: + bias + channel + pe ----
    const float* bias = (pl == 16) ? b16 : (pl == 32) ? b32 : (pl == 64) ? b64 : b128;
    float4 bcA, bcB;
    {
        float4 ba = *reinterpret_cast<const float4*>(bias + c0);
        float4 bb = *reinterpret_cast<const float4*>(bias + c0 + 4);
        float4 ca = *reinterpret_cast<const float4*>(chan + v * DM + c0);
        float4 cb = *reinterpret_cast<const float4*>(chan + v * DM + c0 + 4);
        bcA.x = ba.x + ca.x; bcA.y = ba.y + ca.y; bcA.z = ba.z + ca.z; bcA.w = ba.w + ca.w;
        bcB.x = bb.x + cb.x; bcB.y = bb.y + cb.y; bcB.z = bb.z + cb.z; bcB.w = bb.w + cb.w;
    }

    const int row0 = i0 + wv * 8;
    float* ob = out + ((size_t)(b * TOK + c_tokoff[v] + row0)) * DM + c0;
    const float* pb = ws /*pe*/ + (size_t)row0 * DM + c0;
#pragma unroll
    for (int r = 0; r < 8; ++r) {
        float4 pA = *reinterpret_cast<const float4*>(pb + (size_t)r * DM);
        float4 pB = *reinterpret_cast<const float4*>(pb + (size_t)r * DM + 4);
        float4 oA, oB;
        oA.x = acc[r][0] + bcA.x + pA.x;
        oA.y = acc[r][1] + bcA.y + pA.y;
        oA.z = acc[r][2] + bcA.z + pA.z;
        oA.w = acc[r][3] + bcA.w + pA.w;
        oB.x = acc[r][4] + bcB.x + pB.x;
        oB.y = acc[r][5] + bcB.y + pB.y;
        oB.z = acc[r][6] + bcB.z + pB.z;
        oB.w = acc[r][7] + bcB.w + pB.w;
        *reinterpret_cast<float4*>(ob + (size_t)r * DM)     = oA;
        *reinterpret_cast<float4*>(ob + (size_t)r * DM + 4) = oB;
    }
}

extern "C" void kernel_launch(void* const* d_in, const int* in_sizes, int n_in,
                              void* d_out, int out_size, void* d_ws, size_t ws_size,
                              hipStream_t stream) {
    const float* x    = (const float*)d_in[0];
    const float* w16  = (const float*)d_in[1];
    const float* b16  = (const float*)d_in[2];
    const float* w32  = (const float*)d_in[3];
    const float* b32  = (const float*)d_in[4];
    const float* w64  = (const float*)d_in[5];
    const float* b64  = (const float*)d_in[6];
    const float* w128 = (const float*)d_in[7];
    const float* b128 = (const float*)d_in[8];
    const float* glb  = (const float*)d_in[9];
    const float* chan = (const float*)d_in[10];
    float* out = (float*)d_out;
    float* ws  = (float*)d_ws;   // pe fp32 [0,262144) + packed fp16 wt -> 1.29 MB

    hipLaunchKernelGGL(setup_kernel, dim3(632), dim3(512), 0, stream,
                       w16, w32, w64, w128, ws);
    hipLaunchKernelGGL(patch_embed_kernel, dim3(1608), dim3(NTHR),
                       BROWS * 64 * sizeof(unsigned),   // 8 KB dynamic LDS (pl=128)
                       stream,
                       x, b16, b32, b64, b128, glb, chan, ws, out);
}

// Round 7
// 37.854 us; speedup vs baseline: 4.8136x; 1.1317x over previous
//
#include <hip/hip_runtime.h>
#include <math.h>

#define DM 512
#define LSEQ 8192
#define NV 8
#define TOK 1608
#define BROWS 32     // patch rows per block
#define NTHR 256     // 4 waves; wave = 8 rows x 256 cols; thread = 8r x 4c

typedef _Float16 h2 __attribute__((ext_vector_type(2)));
typedef float f4n __attribute__((ext_vector_type(4)));   // native float4 for builtins

// Heavy-first segment order (pl=128 first). seg -> v: {6,7,4,5,2,3,0,1}
__device__ __constant__ int c_segv[8]   = {6, 7, 4, 5, 2, 3, 0, 1};
// blocks/seg = 2 col-halves * 32 batches * (n_p/32): 64,64,256,256,256,256,1024,1024
__device__ __constant__ int c_cum[9]    = {0, 64, 128, 384, 640, 896, 1152, 2176, 3200};
__device__ __constant__ int c_lgch[8]   = {0, 0, 2, 2, 2, 2, 4, 4};   // log2(chunks/batch)
// indexed by v:
__device__ __constant__ int c_tokoff[8] = {0, 513, 1026, 1155, 1284, 1413, 1542, 1575};
__device__ __constant__ int c_np[8]     = {512, 512, 128, 128, 128, 128, 32, 32};
__device__ __constant__ int c_pl[8]     = {16, 16, 32, 32, 64, 64, 128, 128};
__device__ __constant__ int c_sf[8]     = {1, 1, 2, 2, 1, 1, 2, 2};
// packed-half2-weight word offsets within d_ws per v; pe occupies words [0,262144)
__device__ __constant__ int c_wtoff[8]  = {262144, 262144, 266240, 266240,
                                           274432, 274432, 290816, 290816};

__device__ __forceinline__ float fdot2f(h2 a, h2 b, float c) {
#if __has_builtin(__builtin_amdgcn_fdot2)
    return __builtin_amdgcn_fdot2(a, b, c, false);
#else
    return fmaf((float)a.y, (float)b.y, fmaf((float)a.x, (float)b.x, c));
#endif
}
__device__ __forceinline__ h2 bch2(unsigned u) { return __builtin_bit_cast(h2, u); }

__device__ __forceinline__ void nt_store4(float* p, float4 v) {
#if __has_builtin(__builtin_nontemporal_store)
    f4n t; t.x = v.x; t.y = v.y; t.z = v.z; t.w = v.w;
    __builtin_nontemporal_store(t, reinterpret_cast<f4n*>(p));
#else
    *reinterpret_cast<float4*>(p) = v;
#endif
}

// ---------------------------------------------------------------------------
// Setup: blocks [0,512) build pe[512][512] fp32 (numpy-matched sinusoidal);
// blocks [512,632) pack transposed fp16 weights wt_h[k2][512] (half2 words).
// ---------------------------------------------------------------------------
__global__ __launch_bounds__(512) void setup_kernel(
    const float* __restrict__ w16, const float* __restrict__ w32,
    const float* __restrict__ w64, const float* __restrict__ w128,
    float* __restrict__ ws)
{
    int bid = blockIdx.x;
    int d = threadIdx.x;
    if (bid < 512) {
        int idx = bid * 512 + d;
        int i = idx >> 9;
        int dd = idx & (DM - 1);
        const float c = -9.210340371976184f / 512.0f;  // -ln(10000)/D
        float div = expf((float)(dd & ~1) * c);
        float ang = (float)i * div;
        ws[idx] = (dd & 1) ? cosf(ang) : sinf(ang);
        return;
    }
    int j = bid - 512;                 // 120 half2-rows across the 4 matrices
    const float* w; int pl, k2, off;
    if (j < 8)       { w = w16;  pl = 16;  k2 = j;      off = 262144; }
    else if (j < 24) { w = w32;  pl = 32;  k2 = j - 8;  off = 266240; }
    else if (j < 56) { w = w64;  pl = 64;  k2 = j - 24; off = 274432; }
    else             { w = w128; pl = 128; k2 = j - 56; off = 290816; }
    float2 p = *reinterpret_cast<const float2*>(w + (size_t)d * pl + 2 * k2);
    h2 h; h.x = (_Float16)p.x; h.y = (_Float16)p.y;
    reinterpret_cast<unsigned*>(ws)[off + k2 * DM + d] = __builtin_bit_cast(unsigned, h);
}

// ---------------------------------------------------------------------------
// Main kernel. Blocks [0,3200): 32 rows x 256 cols (col-half h = local&1);
// thread = 8 rows x 4 cols, fp16 dot2, fp32 epilogue. [3200,3208): global toks.
// ---------------------------------------------------------------------------
__global__ __launch_bounds__(NTHR, 5) void patch_embed_kernel(
    const float* __restrict__ x,
    const float* __restrict__ b16,  const float* __restrict__ b32,
    const float* __restrict__ b64,  const float* __restrict__ b128,
    const float* __restrict__ glb,  const float* __restrict__ chan,
    const float* __restrict__ ws,   float* __restrict__ out)
{
    extern __shared__ float ldsf[];              // 32 rows * pl/2 half2 words, <= 8 KB
    unsigned* ldsu = reinterpret_cast<unsigned*>(ldsf);
    int bid = blockIdx.x;
    const int tid = threadIdx.x;

    if (bid >= 3200) {                           // global-token rows (8 blocks)
        int v = bid - 3200;
        int d2 = tid << 1;
        float2 g = *reinterpret_cast<const float2*>(glb + d2);
        float2 c = *reinterpret_cast<const float2*>(chan + v * DM + d2);
        float2 o; o.x = g.x + c.x; o.y = g.y + c.y;
        int row0 = c_tokoff[v] + c_np[v];
        for (int b = 0; b < 32; ++b)
            *reinterpret_cast<float2*>(out + ((size_t)(b * TOK + row0)) * DM + d2) = o;
        return;
    }

    // ---- block -> (v, h, b, chunk), block-uniform scalar work ----
    int seg = 0;
    while (bid >= c_cum[seg + 1]) ++seg;
    int local = bid - c_cum[seg];
    int v = c_segv[seg];
    int h = local & 1;                           // column half
    int rest = local >> 1;
    int lg = c_lgch[seg];
    int b = rest >> lg;
    int chunk = rest & ((1 << lg) - 1);
    const int pl = c_pl[v];
    const int sf = c_sf[v];
    const int pl2 = pl >> 1;
    const int i0 = chunk * BROWS;

    // ---- stage 32 packed patches into LDS as half2 (sampling folded) ----
    const int ne2 = (BROWS * pl) >> 1;           // half2 words
    const float* xb = x + ((size_t)b * NV + v) * LSEQ + (size_t)i0 * (pl * sf);
    if (sf == 1) {
        for (int t = tid; t < (ne2 >> 1); t += NTHR) {   // t = one float4 = 2 words
            float4 q = *reinterpret_cast<const float4*>(xb + 4 * t);
            h2 a; a.x = (_Float16)q.x; a.y = (_Float16)q.y;
            h2 c; c.x = (_Float16)q.z; c.y = (_Float16)q.w;
            uint2 o; o.x = __builtin_bit_cast(unsigned, a);
            o.y = __builtin_bit_cast(unsigned, c);
            *reinterpret_cast<uint2*>(ldsu + 2 * t) = o;
        }
    } else {
        for (int p = tid; p < ne2; p += NTHR) {          // one word per float4
            float4 q = *reinterpret_cast<const float4*>(xb + 4 * p);
            h2 a; a.x = (_Float16)q.x; a.y = (_Float16)q.z;
            ldsu[p] = __builtin_bit_cast(unsigned, a);
        }
    }
    __syncthreads();

    // ---- per-thread geometry ----
    const int lane = tid & 63;
    const int wv   = tid >> 6;                   // wave -> rows [8wv, 8wv+8)
    const int c0   = (h << 8) + (lane << 2);     // 4 consecutive cols in half h
    const unsigned* prow = ldsu + (wv * 8) * pl2;
    const unsigned* wtv  = reinterpret_cast<const unsigned*>(ws) + c_wtoff[v];

    float acc[8][4];
#pragma unroll
    for (int r = 0; r < 8; ++r)
#pragma unroll
        for (int c = 0; c < 4; ++c) acc[r][c] = 0.f;

    // ---- K loop: 2 half2-rows (4 k) per iter; W prefetched one iter ahead ----
    uint4 w0 = *reinterpret_cast<const uint4*>(wtv + c0);
    uint4 w1 = *reinterpret_cast<const uint4*>(wtv + DM + c0);

    for (int k2 = 0; k2 < pl2; k2 += 2) {
        uint4 n0, n1;
        if (k2 + 2 < pl2) {
            const unsigned* wn = wtv + (k2 + 2) * DM;
            n0 = *reinterpret_cast<const uint4*>(wn + c0);
            n1 = *reinterpret_cast<const uint4*>(wn + DM + c0);
        }
        uint2 pr[8];
#pragma unroll
        for (int r = 0; r < 8; ++r)
            pr[r] = *reinterpret_cast<const uint2*>(prow + r * pl2 + k2);
#pragma unroll
        for (int r = 0; r < 8; ++r) {
            h2 p0 = bch2(pr[r].x);
            h2 p1 = bch2(pr[r].y);
            acc[r][0] = fdot2f(p1, bch2(w1.x), fdot2f(p0, bch2(w0.x), acc[r][0]));
            acc[r][1] = fdot2f(p1, bch2(w1.y), fdot2f(p0, bch2(w0.y), acc[r][1]));
            acc[r][2] = fdot2f(p1, bch2(w1.z), fdot2f(p0, bch2(w0.z), acc[r][2]));
            acc[r][3] = fdot2f(p1, bch2(w1.w), fdot2f(p0, bch2(w0.w), acc[r][3]));
        }
        w0 = n0; w1 = n1;
    }

    // ---- fp32 epilogue: + bias + channel + pe, nontemporal float4 stores ----
    const float* bias = (pl == 16) ? b16 : (pl == 32) ? b32 : (pl == 64) ? b64 : b128;
    float4 bc;
    {
        float4 ba = *reinterpret_cast<const float4*>(bias + c0);
        float4 ca = *reinterpret_cast<const float4*>(chan + v * DM + c0);
        bc.x = ba.x + ca.x; bc.y = ba.y + ca.y;
        bc.z = ba.z + ca.z; bc.w = ba.w + ca.w;
    }

    const int row0 = i0 + wv * 8;
    float* ob = out + ((size_t)(b * TOK + c_tokoff[v] + row0)) * DM + c0;
    const float* pb = ws /*pe*/ + (size_t)row0 * DM + c0;
#pragma unroll
    for (int r = 0; r < 8; ++r) {
        float4 pA = *reinterpret_cast<const float4*>(pb + (size_t)r * DM);
        float4 o;
        o.x = acc[r][0] + bc.x + pA.x;
        o.y = acc[r][1] + bc.y + pA.y;
        o.z = acc[r][2] + bc.z + pA.z;
        o.w = acc[r][3] + bc.w + pA.w;
        nt_store4(ob + (size_t)r * DM, o);
    }
}

extern "C" void kernel_launch(void* const* d_in, const int* in_sizes, int n_in,
                              void* d_out, int out_size, void* d_ws, size_t ws_size,
                              hipStream_t stream) {
    const float* x    = (const float*)d_in[0];
    const float* w16  = (const float*)d_in[1];
    const float* b16  = (const float*)d_in[2];
    const float* w32  = (const float*)d_in[3];
    const float* b32  = (const float*)d_in[4];
    const float* w64  = (const float*)d_in[5];
    const float* b64  = (const float*)d_in[6];
    const float* w128 = (const float*)d_in[7];
    const float* b128 = (const float*)d_in[8];
    const float* glb  = (const float*)d_in[9];
    const float* chan = (const float*)d_in[10];
    float* out = (float*)d_out;
    float* ws  = (float*)d_ws;   // pe fp32 [0,262144) + packed fp16 wt -> 1.29 MB

    hipLaunchKernelGGL(setup_kernel, dim3(632), dim3(512), 0, stream,
                       w16, w32, w64, w128, ws);
    hipLaunchKernelGGL(patch_embed_kernel, dim3(3208), dim3(NTHR),
                       BROWS * 64 * sizeof(unsigned),   // 8 KB dynamic LDS (pl=128)
                       stream,
                       x, b16, b32, b64, b128, glb, chan, ws, out);
}